// Round 18
// baseline (349.062 us; speedup 1.0000x reference)
//
#include <hip/hip_runtime.h>

#define NN 100000
#define NE 1600000
#define NBK 391                     // buckets of 256 dst nodes
#define CHUNK 8192
#define NBLK ((NE + CHUNK - 1) / CHUNK)   // 196
#define MPAD 100096                 // NN padded to multiple of 128
#define CASTB 12500                 // (NN*128/4) float4 / 256 threads
#define PREPB (CASTB + 128 + 128 + 48)    // 12804
#define GBLK 2048                   // gather blocks (8192 waves)
#define NPW ((NN + 8191) / 8192)    // nodes per wave = 13

using bf16x8 = __attribute__((ext_vector_type(8))) short;
using f32x4  = __attribute__((ext_vector_type(4))) float;

typedef const __attribute__((address_space(1))) unsigned int* gas_t;
typedef __attribute__((address_space(3))) unsigned int* las_t;

static __device__ __forceinline__ unsigned short f2bf(float f) {
    unsigned int u = __float_as_uint(f);
    unsigned int r = (u + 0x7FFFu + ((u >> 16) & 1u)) >> 16;   // RNE
    return (unsigned short)r;
}
static __device__ __forceinline__ float lo16(unsigned int u) {
    return __uint_as_float(u << 16);
}
static __device__ __forceinline__ float hi16(unsigned int u) {
    return __uint_as_float(u & 0xFFFF0000u);
}
static __device__ __forceinline__ unsigned int pk(float lo, float hi) {
    return ((unsigned int)f2bf(hi) << 16) | (unsigned int)f2bf(lo);
}

// ============ CSR hist + all prep work in one launch ============

__global__ __launch_bounds__(256) void k_hist_prep(
        const int* __restrict__ dst, int* __restrict__ ghist,
        const float4* __restrict__ x4, ushort4* __restrict__ XB4,
        const float* __restrict__ Ws0, const float* __restrict__ Wn0,
        unsigned short* __restrict__ BT0,
        const float* __restrict__ Ws1, const float* __restrict__ Wn1,
        unsigned short* __restrict__ BT1,
        const float* __restrict__ Ws2, const float* __restrict__ Wn2,
        unsigned short* __restrict__ BT2) {
    __shared__ int h[NBK];
    int bid = blockIdx.x, t = threadIdx.x;
    if (bid < NBLK) {
        for (int i = t; i < NBK; i += 256) h[i] = 0;
        __syncthreads();
        int beg = bid * CHUNK, end = min(beg + CHUNK, NE);
        for (int i = beg + t; i < end; i += 256)
            atomicAdd(&h[dst[i] >> 8], 1);
        __syncthreads();
        for (int i = t; i < NBK; i += 256) ghist[bid * NBK + i] = h[i];
        return;
    }
    int pb = bid - NBLK;
    if (pb < CASTB) {
        int i = pb * 256 + t;
        float4 v = x4[i];
        ushort4 o;
        o.x = f2bf(v.x); o.y = f2bf(v.y); o.z = f2bf(v.z); o.w = f2bf(v.w);
        XB4[i] = o;
    } else if (pb < CASTB + 128) {
        int idx = (pb - CASTB) * 256 + t;
        int k = idx >> 7, n = idx & 127;
        float v = (k < 128) ? Ws0[k * 128 + n] : Wn0[(k - 128) * 128 + n];
        BT0[n * 256 + k] = f2bf(v);
    } else if (pb < CASTB + 256) {
        int idx = (pb - CASTB - 128) * 256 + t;
        int k = idx >> 7, n = idx & 127;
        float v = (k < 128) ? Ws1[k * 128 + n] : Wn1[(k - 128) * 128 + n];
        BT1[n * 256 + k] = f2bf(v);
    } else {
        int idx = (pb - CASTB - 256) * 256 + t;
        if (idx < 96 * 128) {
            int n = idx >> 7, k = idx & 127;
            float v = 0.f;
            if (n < 48) { if (n < 47) v = Ws2[k * 47 + n]; }
            else        { int cc = n - 48; if (cc < 47) v = Wn2[k * 47 + cc]; }
            BT2[n * 128 + k] = f2bf(v);
        }
    }
}

// single block: bucket totals -> boff (exclusive), per-(block,bucket) bases
__global__ __launch_bounds__(512) void k_basescan(const int* __restrict__ ghist,
                                                  int* __restrict__ boff,
                                                  int* __restrict__ gbase) {
    __shared__ int s[512];
    int t = threadIdx.x;
    int tot = 0;
    if (t < NBK) {
#pragma unroll 4
        for (int blk = 0; blk < NBLK; ++blk) tot += ghist[blk * NBK + t];
    }
    s[t] = tot;
    __syncthreads();
    for (int o = 1; o < 512; o <<= 1) {
        int u = (t >= o) ? s[t - o] : 0;
        __syncthreads();
        s[t] += u;
        __syncthreads();
    }
    int base = s[t] - tot;
    if (t <= NBK) boff[t] = base;
    if (t < NBK) {
        int run = base;
        for (int blk = 0; blk < NBLK; ++blk) {
            int g = ghist[blk * NBK + t];
            gbase[blk * NBK + t] = run;
            run += g;
        }
    }
}

__global__ __launch_bounds__(256) void k_scatter(const int* __restrict__ src,
                                                 const int* __restrict__ dst,
                                                 const int* __restrict__ gbase,
                                                 unsigned int* __restrict__ eb) {
    __shared__ int cur[NBK];
    int b = blockIdx.x, t = threadIdx.x;
    for (int i = t; i < NBK; i += 256) cur[i] = gbase[b * NBK + i];
    __syncthreads();
    int beg = b * CHUNK, end = min(beg + CHUNK, NE);
    for (int i = beg + t; i < end; i += 256) {
        int d = dst[i];
        int p = atomicAdd(&cur[d >> 8], 1);
        eb[p] = ((unsigned int)(d & 255) << 24) | (unsigned int)src[i];
    }
}

// fused: per-bucket degree hist -> LDS scan -> row_ptr -> col fill
__global__ __launch_bounds__(256) void k_csr(const unsigned int* __restrict__ eb,
                                             const int* __restrict__ boff,
                                             int* __restrict__ rp,
                                             int* __restrict__ col) {
    __shared__ int h[256];
    __shared__ int sc[256];
    __shared__ int cur[256];
    int b = blockIdx.x, t = threadIdx.x;
    h[t] = 0;
    __syncthreads();
    int beg = boff[b], end = boff[b + 1];
    for (int e = beg + t; e < end; e += 256)
        atomicAdd(&h[eb[e] >> 24], 1);
    __syncthreads();
    int c = h[t];
    sc[t] = c;
    __syncthreads();
    for (int o = 1; o < 256; o <<= 1) {
        int v = (t >= o) ? sc[t - o] : 0;
        __syncthreads();
        sc[t] += v;
        __syncthreads();
    }
    int excl = beg + sc[t] - c;
    int node = (b << 8) + t;
    if (node < NN) rp[node] = excl;
    if (node == NN - 1) rp[NN] = NE;
    cur[t] = excl;
    __syncthreads();
    for (int e = beg + t; e < end; e += 256) {
        unsigned int p = eb[e];
        int pos = atomicAdd(&cur[p >> 24], 1);
        col[pos] = (int)(p & 0xFFFFFFu);
    }
}

// ======== mean-aggregate gather 128-feat: quarter-wave uint4, 4 edges/instr ========

__global__ __launch_bounds__(256) void k_gather128(
        const uint4* __restrict__ hb4,   // [node][16] uint4 (256B bf16 rows)
        const int* __restrict__ rp, const int* __restrict__ col,
        uint4* __restrict__ hnb4) {
    int wave = blockIdx.x * 4 + (threadIdx.x >> 6);
    int lane = threadIdx.x & 63;
    int q = lane >> 4, l16 = lane & 15;
    int n0 = wave * NPW;
    int n1 = min(n0 + NPW, NN);
    for (int node = n0; node < n1; ++node) {
        int beg = rp[node], end = rp[node + 1];
        float a0 = 0.f, a1 = 0.f, a2 = 0.f, a3 = 0.f;
        float a4 = 0.f, a5 = 0.f, a6 = 0.f, a7 = 0.f;
        float b0 = 0.f, b1 = 0.f, b2 = 0.f, b3 = 0.f;
        float b4 = 0.f, b5 = 0.f, b6 = 0.f, b7 = 0.f;
        int e = beg;
        for (; e + 8 <= end; e += 8) {
            int c0 = col[e + q];
            int c1 = col[e + 4 + q];
            uint4 v0 = hb4[(size_t)c0 * 16 + l16];
            uint4 v1 = hb4[(size_t)c1 * 16 + l16];
            a0 += lo16(v0.x); a1 += hi16(v0.x); a2 += lo16(v0.y); a3 += hi16(v0.y);
            a4 += lo16(v0.z); a5 += hi16(v0.z); a6 += lo16(v0.w); a7 += hi16(v0.w);
            b0 += lo16(v1.x); b1 += hi16(v1.x); b2 += lo16(v1.y); b3 += hi16(v1.y);
            b4 += lo16(v1.z); b5 += hi16(v1.z); b6 += lo16(v1.w); b7 += hi16(v1.w);
        }
        for (; e < end; e += 4) {
            if (e + q < end) {
                uint4 v = hb4[(size_t)col[e + q] * 16 + l16];
                a0 += lo16(v.x); a1 += hi16(v.x); a2 += lo16(v.y); a3 += hi16(v.y);
                a4 += lo16(v.z); a5 += hi16(v.z); a6 += lo16(v.w); a7 += hi16(v.w);
            }
        }
        float s0 = a0 + b0, s1 = a1 + b1, s2 = a2 + b2, s3 = a3 + b3;
        float s4 = a4 + b4, s5 = a5 + b5, s6 = a6 + b6, s7 = a7 + b7;
        s0 += __shfl_xor(s0, 16); s0 += __shfl_xor(s0, 32);
        s1 += __shfl_xor(s1, 16); s1 += __shfl_xor(s1, 32);
        s2 += __shfl_xor(s2, 16); s2 += __shfl_xor(s2, 32);
        s3 += __shfl_xor(s3, 16); s3 += __shfl_xor(s3, 32);
        s4 += __shfl_xor(s4, 16); s4 += __shfl_xor(s4, 32);
        s5 += __shfl_xor(s5, 16); s5 += __shfl_xor(s5, 32);
        s6 += __shfl_xor(s6, 16); s6 += __shfl_xor(s6, 32);
        s7 += __shfl_xor(s7, 16); s7 += __shfl_xor(s7, 32);
        if (q == 0) {
            float d = (float)(end - beg);
            float inv = (d > 0.f) ? 1.0f / d : 0.0f;
            uint4 o;
            o.x = pk(s0 * inv, s1 * inv);
            o.y = pk(s2 * inv, s3 * inv);
            o.z = pk(s4 * inv, s5 * inv);
            o.w = pk(s6 * inv, s7 * inv);
            hnb4[(size_t)node * 16 + l16] = o;
        }
    }
}

// ===== MFMA GEMM, BM=128, 4 waves 2x2, LDS-staged A-tiles =====
// outB = bf16(relu([A0|A1] @ BT^T + b)).  A-tile staged via global_load_lds
// with XOR-swizzled SOURCE (chunk ^= row&7); reads apply the same XOR.

__global__ __launch_bounds__(256, 2) void k_mgemm(
        const unsigned short* __restrict__ A0,
        const unsigned short* __restrict__ A1,
        const unsigned short* __restrict__ BT,
        const float* __restrict__ bias,
        unsigned short* __restrict__ outB) {
    __shared__ char sA[32768];      // 128 rows x 256B
    int t = threadIdx.x;
    int lane = t & 63, wid = t >> 6;
    int wm = wid >> 1, wn = wid & 1;
    int lr = lane & 15, lg = lane >> 4;
    int brow = blockIdx.x * 128;
    int row0 = brow + wm * 64;
    int colw = wn * 64;
    f32x4 zero = {0.f, 0.f, 0.f, 0.f};
    f32x4 acc[4][4];
#pragma unroll
    for (int a = 0; a < 4; ++a)
#pragma unroll
        for (int b = 0; b < 4; ++b) acc[a][b] = zero;

#pragma unroll 1
    for (int p = 0; p < 2; ++p) {
        const unsigned short* A = p ? A1 : A0;
        // ---- async stage: 8 x 1KB per wave, swizzled source chunks ----
#pragma unroll
        for (int it = 0; it < 8; ++it) {
            int rl = wid * 32 + it * 4 + (lane >> 4);
            int ch = (lane & 15) ^ (rl & 7);
            const char* src = (const char*)A + (size_t)(brow + rl) * 256 + ch * 16;
            __builtin_amdgcn_global_load_lds((gas_t)src,
                (las_t)(sA + wid * 8192 + it * 1024), 16, 0, 0);
        }
        __syncthreads();            // drain vmcnt: tile ready
        bf16x8 bReg[4][4];
#pragma unroll
        for (int nf = 0; nf < 4; ++nf)
#pragma unroll
            for (int ks = 0; ks < 4; ++ks)
                bReg[nf][ks] = *(const bf16x8*)&BT[(size_t)(colw + nf * 16 + lr) * 256 + p * 128 + ks * 32 + lg * 8];
#pragma unroll
        for (int mf = 0; mf < 4; ++mf) {
            int rl = wm * 64 + mf * 16 + lr;
            bf16x8 aReg[4];
#pragma unroll
            for (int ks = 0; ks < 4; ++ks)
                aReg[ks] = *(const bf16x8*)&sA[rl * 256 + (((ks * 4 + lg) ^ (rl & 7)) << 4)];
#pragma unroll
            for (int ks = 0; ks < 4; ++ks)
#pragma unroll
                for (int nf = 0; nf < 4; ++nf)
                    acc[mf][nf] = __builtin_amdgcn_mfma_f32_16x16x32_bf16(
                        aReg[ks], bReg[nf][ks], acc[mf][nf], 0, 0, 0);
        }
        __syncthreads();            // all sA reads done before restage / epilogue
    }
    // in-place write (A0 fully consumed during p=0 staging)
#pragma unroll
    for (int nf = 0; nf < 4; ++nf) {
        int cidx = colw + nf * 16 + lr;
        float bb = bias[cidx];
#pragma unroll
        for (int mf = 0; mf < 4; ++mf) {
#pragma unroll
            for (int j = 0; j < 4; ++j) {
                int row = row0 + mf * 16 + lg * 4 + j;
                if (row < NN) {
                    float v = fmaxf(acc[mf][nf][j] + bb, 0.f);
                    outB[(size_t)row * 128 + cidx] = f2bf(v);
                }
            }
        }
    }
}

// ===== layer 2 MFMA, BM=128, LDS-staged: S = h2@Ws2+b2 (fp32), TB = h2@Wn2 (bf16) =====

__global__ __launch_bounds__(256, 2) void k_mgemm47s(
        const unsigned short* __restrict__ A,     // [MPAD][128] bf16 h2
        const unsigned short* __restrict__ BT2,   // [96][128]
        const float* __restrict__ bias,
        float* __restrict__ S,
        unsigned short* __restrict__ TB) {
    __shared__ char sA[32768];
    int t = threadIdx.x;
    int lane = t & 63, wid = t >> 6;
    int wm = wid >> 1, wn = wid & 1;
    int lr = lane & 15, lg = lane >> 4;
    int brow = blockIdx.x * 128;
    int row0 = brow + wm * 64;
    int colw = wn * 48;
    // ---- stage A-tile (K=128, one phase) ----
#pragma unroll
    for (int it = 0; it < 8; ++it) {
        int rl = wid * 32 + it * 4 + (lane >> 4);
        int ch = (lane & 15) ^ (rl & 7);
        const char* src = (const char*)A + (size_t)(brow + rl) * 256 + ch * 16;
        __builtin_amdgcn_global_load_lds((gas_t)src,
            (las_t)(sA + wid * 8192 + it * 1024), 16, 0, 0);
    }
    __syncthreads();
    f32x4 zero = {0.f, 0.f, 0.f, 0.f};
    f32x4 acc[4][3];
#pragma unroll
    for (int a = 0; a < 4; ++a)
#pragma unroll
        for (int b = 0; b < 3; ++b) acc[a][b] = zero;
    bf16x8 bReg[3][4];
#pragma unroll
    for (int nf = 0; nf < 3; ++nf)
#pragma unroll
        for (int ks = 0; ks < 4; ++ks)
            bReg[nf][ks] = *(const bf16x8*)&BT2[(size_t)(colw + nf * 16 + lr) * 128 + ks * 32 + lg * 8];
#pragma unroll
    for (int mf = 0; mf < 4; ++mf) {
        int rl = wm * 64 + mf * 16 + lr;
        bf16x8 aReg[4];
#pragma unroll
        for (int ks = 0; ks < 4; ++ks)
            aReg[ks] = *(const bf16x8*)&sA[rl * 256 + (((ks * 4 + lg) ^ (rl & 7)) << 4)];
#pragma unroll
        for (int ks = 0; ks < 4; ++ks)
#pragma unroll
            for (int nf = 0; nf < 3; ++nf)
                acc[mf][nf] = __builtin_amdgcn_mfma_f32_16x16x32_bf16(
                    aReg[ks], bReg[nf][ks], acc[mf][nf], 0, 0, 0);
    }
#pragma unroll
    for (int nf = 0; nf < 3; ++nf) {
        int cidx = colw + nf * 16 + lr;      // 0..95
#pragma unroll
        for (int mf = 0; mf < 4; ++mf) {
#pragma unroll
            for (int j = 0; j < 4; ++j) {
                int row = row0 + mf * 16 + lg * 4 + j;
                if (row < NN) {
                    float v = acc[mf][nf][j];
                    if (cidx < 47)
                        S[(size_t)row * 48 + cidx] = v + bias[cidx];
                    else if (cidx >= 48)
                        TB[(size_t)row * 64 + (cidx - 48)] = f2bf(v);   // 128B padded rows
                }
            }
        }
    }
}

// ======== layer-2 aggregate: out = S + mean(TB), quarter-wave uint2 (full 128B row) ========

__global__ __launch_bounds__(256) void k_gather47(
        const uint2* __restrict__ TB2,   // [node][16] uint2 (128B padded bf16 rows)
        const float4* __restrict__ S4,   // [node][12] float4 (48 fp32)
        const int* __restrict__ rp, const int* __restrict__ col,
        float* __restrict__ out) {
    int wave = blockIdx.x * 4 + (threadIdx.x >> 6);
    int lane = threadIdx.x & 63;
    int q = lane >> 4, l16 = lane & 15;
    int n0 = wave * NPW;
    int n1 = min(n0 + NPW, NN);
    for (int node = n0; node < n1; ++node) {
        int beg = rp[node], end = rp[node + 1];
        float a0 = 0.f, a1 = 0.f, a2 = 0.f, a3 = 0.f;
        float b0 = 0.f, b1 = 0.f, b2 = 0.f, b3 = 0.f;
        int e = beg;
        for (; e + 8 <= end; e += 8) {
            int i0 = col[e + q];
            int i1 = col[e + 4 + q];
            uint2 u0 = TB2[(size_t)i0 * 16 + l16];
            uint2 u1 = TB2[(size_t)i1 * 16 + l16];
            a0 += lo16(u0.x); a1 += hi16(u0.x); a2 += lo16(u0.y); a3 += hi16(u0.y);
            b0 += lo16(u1.x); b1 += hi16(u1.x); b2 += lo16(u1.y); b3 += hi16(u1.y);
        }
        for (; e < end; e += 4) {
            if (e + q < end) {
                uint2 u = TB2[(size_t)col[e + q] * 16 + l16];
                a0 += lo16(u.x); a1 += hi16(u.x); a2 += lo16(u.y); a3 += hi16(u.y);
            }
        }
        float s0 = a0 + b0, s1 = a1 + b1, s2 = a2 + b2, s3 = a3 + b3;
        s0 += __shfl_xor(s0, 16); s0 += __shfl_xor(s0, 32);
        s1 += __shfl_xor(s1, 16); s1 += __shfl_xor(s1, 32);
        s2 += __shfl_xor(s2, 16); s2 += __shfl_xor(s2, 32);
        s3 += __shfl_xor(s3, 16); s3 += __shfl_xor(s3, 32);
        if (q == 0 && l16 < 12) {
            float d = (float)(end - beg);
            float inv = (d > 0.f) ? 1.0f / d : 0.0f;
            float4 sv = S4[(size_t)node * 12 + l16];
            int c = l16 * 4;
            out[(size_t)node * 47 + c]     = sv.x + s0 * inv;
            out[(size_t)node * 47 + c + 1] = sv.y + s1 * inv;
            out[(size_t)node * 47 + c + 2] = sv.z + s2 * inv;
            if (c + 3 < 47) out[(size_t)node * 47 + c + 3] = sv.w + s3 * inv;
        }
    }
}

// ================= launcher =================

static inline size_t align_up(size_t x, size_t a) { return (x + a - 1) / a * a; }

extern "C" void kernel_launch(void* const* d_in, const int* in_sizes, int n_in,
                              void* d_out, int out_size, void* d_ws, size_t ws_size,
                              hipStream_t stream) {
    const float* x   = (const float*)d_in[0];
    const int* src   = (const int*)d_in[1];
    const int* dst   = (const int*)d_in[2];
    const float* Ws0 = (const float*)d_in[3];
    const float* Wn0 = (const float*)d_in[4];
    const float* b0  = (const float*)d_in[5];
    const float* Ws1 = (const float*)d_in[6];
    const float* Wn1 = (const float*)d_in[7];
    const float* b1  = (const float*)d_in[8];
    const float* Ws2 = (const float*)d_in[9];
    const float* Wn2 = (const float*)d_in[10];
    const float* b2  = (const float*)d_in[11];
    float* out = (float*)d_out;

    char* ws = (char*)d_ws;
    size_t off = 0;
    auto alloc = [&](size_t bytes) -> void* {
        void* p = ws + off; off = align_up(off + bytes, 256); return p;
    };
    int* row_ptr = (int*)alloc((size_t)(NN + 1) * 4);
    int* boff    = (int*)alloc((size_t)(NBK + 1) * 4);
    int* gbase   = (int*)alloc((size_t)NBLK * NBK * 4);
    int* ghist   = (int*)alloc((size_t)NBLK * NBK * 4);
    int* col     = (int*)alloc((size_t)NE * 4);
    unsigned short* XB  = (unsigned short*)alloc((size_t)MPAD * 128 * 2);   // 25.6MB
    unsigned short* BT0 = (unsigned short*)alloc(128 * 256 * 2);
    unsigned short* BT1 = (unsigned short*)alloc(128 * 256 * 2);
    unsigned short* BT2 = (unsigned short*)alloc(96 * 128 * 2);
    unsigned int* HNB   = (unsigned int*)alloc((size_t)MPAD * 128 * 2);     // 25.6MB (gather out)
    // S+TB region; eb (CSR build, 6.4MB) time-shares its head (dead before S/TB written)
    size_t sbytes  = (size_t)NN * 48 * 4;          // 19.2MB fp32 S
    size_t tbbytes = (size_t)MPAD * 64 * 2;        // 12.8MB bf16 TB (128B rows)
    char* stb = (char*)alloc(sbytes + tbbytes);
    unsigned int* eb   = (unsigned int*)stb;
    float* S           = (float*)stb;
    unsigned short* TB = (unsigned short*)(stb + sbytes);

    // --- CSR build + prep (hist launch also does cast + weight transposes) ---
    k_hist_prep<<<NBLK + PREPB, 256, 0, stream>>>(
        dst, ghist, (const float4*)x, (ushort4*)XB,
        Ws0, Wn0, BT0, Ws1, Wn1, BT1, Ws2, Wn2, BT2);
    k_basescan<<<1, 512, 0, stream>>>(ghist, boff, gbase);
    k_scatter<<<NBLK, 256, 0, stream>>>(src, dst, gbase, eb);
    k_csr<<<NBK, 256, 0, stream>>>(eb, boff, row_ptr, col);

    int mgrid = MPAD / 128;   // 782

    // --- layer 0 (bf16 in-place over XB) ---
    k_gather128<<<GBLK, 256, 0, stream>>>((const uint4*)XB, row_ptr, col, (uint4*)HNB);
    k_mgemm<<<mgrid, 256, 0, stream>>>(XB, (const unsigned short*)HNB, BT0, b0, XB);
    // --- layer 1 (bf16 in-place over XB) ---
    k_gather128<<<GBLK, 256, 0, stream>>>((const uint4*)XB, row_ptr, col, (uint4*)HNB);
    k_mgemm<<<mgrid, 256, 0, stream>>>(XB, (const unsigned short*)HNB, BT1, b1, XB);
    // --- layer 2 (staged transform + aggregate) ---
    k_mgemm47s<<<mgrid, 256, 0, stream>>>(XB, BT2, b2, S, TB);
    k_gather47<<<GBLK, 256, 0, stream>>>((const uint2*)TB, (const float4*)S,
                                         row_ptr, col, out);
}

// Round 19
// 332.849 us; speedup vs baseline: 1.0487x; 1.0487x over previous
//
#include <hip/hip_runtime.h>

#define NN 100000
#define NE 1600000
#define NBK 391                     // buckets of 256 dst nodes
#define CHUNK 8192
#define NBLK ((NE + CHUNK - 1) / CHUNK)   // 196
#define MPAD 100096                 // NN padded to multiple of 128
#define CASTB 12500                 // (NN*128/4) float4 / 256 threads
#define PREPB (CASTB + 128 + 128 + 48)    // 12804
#define GBLK 2048                   // gather blocks (8192 waves)
#define NPW ((NN + 8191) / 8192)    // nodes per wave = 13

using bf16x8 = __attribute__((ext_vector_type(8))) short;
using f32x4  = __attribute__((ext_vector_type(4))) float;

typedef const __attribute__((address_space(1))) unsigned int* gas_t;
typedef __attribute__((address_space(3))) unsigned int* las_t;

static __device__ __forceinline__ unsigned short f2bf(float f) {
    unsigned int u = __float_as_uint(f);
    unsigned int r = (u + 0x7FFFu + ((u >> 16) & 1u)) >> 16;   // RNE
    return (unsigned short)r;
}
static __device__ __forceinline__ float lo16(unsigned int u) {
    return __uint_as_float(u << 16);
}
static __device__ __forceinline__ float hi16(unsigned int u) {
    return __uint_as_float(u & 0xFFFF0000u);
}
static __device__ __forceinline__ unsigned int pk(float lo, float hi) {
    return ((unsigned int)f2bf(hi) << 16) | (unsigned int)f2bf(lo);
}

// ============ CSR hist + all prep work in one launch ============

__global__ __launch_bounds__(256) void k_hist_prep(
        const int* __restrict__ dst, int* __restrict__ ghist,
        const float4* __restrict__ x4, ushort4* __restrict__ XB4,
        const float* __restrict__ Ws0, const float* __restrict__ Wn0,
        unsigned short* __restrict__ BT0,
        const float* __restrict__ Ws1, const float* __restrict__ Wn1,
        unsigned short* __restrict__ BT1,
        const float* __restrict__ Ws2, const float* __restrict__ Wn2,
        unsigned short* __restrict__ BT2) {
    __shared__ int h[NBK];
    int bid = blockIdx.x, t = threadIdx.x;
    if (bid < NBLK) {
        for (int i = t; i < NBK; i += 256) h[i] = 0;
        __syncthreads();
        int beg = bid * CHUNK, end = min(beg + CHUNK, NE);
        for (int i = beg + t; i < end; i += 256)
            atomicAdd(&h[dst[i] >> 8], 1);
        __syncthreads();
        for (int i = t; i < NBK; i += 256) ghist[bid * NBK + i] = h[i];
        return;
    }
    int pb = bid - NBLK;
    if (pb < CASTB) {
        int i = pb * 256 + t;
        float4 v = x4[i];
        ushort4 o;
        o.x = f2bf(v.x); o.y = f2bf(v.y); o.z = f2bf(v.z); o.w = f2bf(v.w);
        XB4[i] = o;
    } else if (pb < CASTB + 128) {
        int idx = (pb - CASTB) * 256 + t;
        int k = idx >> 7, n = idx & 127;
        float v = (k < 128) ? Ws0[k * 128 + n] : Wn0[(k - 128) * 128 + n];
        BT0[n * 256 + k] = f2bf(v);
    } else if (pb < CASTB + 256) {
        int idx = (pb - CASTB - 128) * 256 + t;
        int k = idx >> 7, n = idx & 127;
        float v = (k < 128) ? Ws1[k * 128 + n] : Wn1[(k - 128) * 128 + n];
        BT1[n * 256 + k] = f2bf(v);
    } else {
        int idx = (pb - CASTB - 256) * 256 + t;
        if (idx < 96 * 128) {
            int n = idx >> 7, k = idx & 127;
            float v = 0.f;
            if (n < 48) { if (n < 47) v = Ws2[k * 47 + n]; }
            else        { int cc = n - 48; if (cc < 47) v = Wn2[k * 47 + cc]; }
            BT2[n * 128 + k] = f2bf(v);
        }
    }
}

// single block: bucket totals -> boff (exclusive), per-(block,bucket) bases
__global__ __launch_bounds__(512) void k_basescan(const int* __restrict__ ghist,
                                                  int* __restrict__ boff,
                                                  int* __restrict__ gbase) {
    __shared__ int s[512];
    int t = threadIdx.x;
    int tot = 0;
    if (t < NBK) {
#pragma unroll 4
        for (int blk = 0; blk < NBLK; ++blk) tot += ghist[blk * NBK + t];
    }
    s[t] = tot;
    __syncthreads();
    for (int o = 1; o < 512; o <<= 1) {
        int u = (t >= o) ? s[t - o] : 0;
        __syncthreads();
        s[t] += u;
        __syncthreads();
    }
    int base = s[t] - tot;
    if (t <= NBK) boff[t] = base;
    if (t < NBK) {
        int run = base;
        for (int blk = 0; blk < NBLK; ++blk) {
            int g = ghist[blk * NBK + t];
            gbase[blk * NBK + t] = run;
            run += g;
        }
    }
}

__global__ __launch_bounds__(256) void k_scatter(const int* __restrict__ src,
                                                 const int* __restrict__ dst,
                                                 const int* __restrict__ gbase,
                                                 unsigned int* __restrict__ eb) {
    __shared__ int cur[NBK];
    int b = blockIdx.x, t = threadIdx.x;
    for (int i = t; i < NBK; i += 256) cur[i] = gbase[b * NBK + i];
    __syncthreads();
    int beg = b * CHUNK, end = min(beg + CHUNK, NE);
    for (int i = beg + t; i < end; i += 256) {
        int d = dst[i];
        int p = atomicAdd(&cur[d >> 8], 1);
        eb[p] = ((unsigned int)(d & 255) << 24) | (unsigned int)src[i];
    }
}

// fused: per-bucket degree hist -> LDS scan -> row_ptr -> col fill
__global__ __launch_bounds__(256) void k_csr(const unsigned int* __restrict__ eb,
                                             const int* __restrict__ boff,
                                             int* __restrict__ rp,
                                             int* __restrict__ col) {
    __shared__ int h[256];
    __shared__ int sc[256];
    __shared__ int cur[256];
    int b = blockIdx.x, t = threadIdx.x;
    h[t] = 0;
    __syncthreads();
    int beg = boff[b], end = boff[b + 1];
    for (int e = beg + t; e < end; e += 256)
        atomicAdd(&h[eb[e] >> 24], 1);
    __syncthreads();
    int c = h[t];
    sc[t] = c;
    __syncthreads();
    for (int o = 1; o < 256; o <<= 1) {
        int v = (t >= o) ? sc[t - o] : 0;
        __syncthreads();
        sc[t] += v;
        __syncthreads();
    }
    int excl = beg + sc[t] - c;
    int node = (b << 8) + t;
    if (node < NN) rp[node] = excl;
    if (node == NN - 1) rp[NN] = NE;
    cur[t] = excl;
    __syncthreads();
    for (int e = beg + t; e < end; e += 256) {
        unsigned int p = eb[e];
        int pos = atomicAdd(&cur[p >> 24], 1);
        col[pos] = (int)(p & 0xFFFFFFu);
    }
}

// ======== mean-aggregate gather 128-feat: quarter-wave uint4, 4 edges/instr ========

__global__ __launch_bounds__(256) void k_gather128(
        const uint4* __restrict__ hb4,   // [node][16] uint4 (256B bf16 rows)
        const int* __restrict__ rp, const int* __restrict__ col,
        uint4* __restrict__ hnb4) {
    int wave = blockIdx.x * 4 + (threadIdx.x >> 6);
    int lane = threadIdx.x & 63;
    int q = lane >> 4, l16 = lane & 15;
    int n0 = wave * NPW;
    int n1 = min(n0 + NPW, NN);
    for (int node = n0; node < n1; ++node) {
        int beg = rp[node], end = rp[node + 1];
        float a0 = 0.f, a1 = 0.f, a2 = 0.f, a3 = 0.f;
        float a4 = 0.f, a5 = 0.f, a6 = 0.f, a7 = 0.f;
        float b0 = 0.f, b1 = 0.f, b2 = 0.f, b3 = 0.f;
        float b4 = 0.f, b5 = 0.f, b6 = 0.f, b7 = 0.f;
        int e = beg;
        for (; e + 8 <= end; e += 8) {
            int c0 = col[e + q];
            int c1 = col[e + 4 + q];
            uint4 v0 = hb4[(size_t)c0 * 16 + l16];
            uint4 v1 = hb4[(size_t)c1 * 16 + l16];
            a0 += lo16(v0.x); a1 += hi16(v0.x); a2 += lo16(v0.y); a3 += hi16(v0.y);
            a4 += lo16(v0.z); a5 += hi16(v0.z); a6 += lo16(v0.w); a7 += hi16(v0.w);
            b0 += lo16(v1.x); b1 += hi16(v1.x); b2 += lo16(v1.y); b3 += hi16(v1.y);
            b4 += lo16(v1.z); b5 += hi16(v1.z); b6 += lo16(v1.w); b7 += hi16(v1.w);
        }
        for (; e < end; e += 4) {
            if (e + q < end) {
                uint4 v = hb4[(size_t)col[e + q] * 16 + l16];
                a0 += lo16(v.x); a1 += hi16(v.x); a2 += lo16(v.y); a3 += hi16(v.y);
                a4 += lo16(v.z); a5 += hi16(v.z); a6 += lo16(v.w); a7 += hi16(v.w);
            }
        }
        float s0 = a0 + b0, s1 = a1 + b1, s2 = a2 + b2, s3 = a3 + b3;
        float s4 = a4 + b4, s5 = a5 + b5, s6 = a6 + b6, s7 = a7 + b7;
        s0 += __shfl_xor(s0, 16); s0 += __shfl_xor(s0, 32);
        s1 += __shfl_xor(s1, 16); s1 += __shfl_xor(s1, 32);
        s2 += __shfl_xor(s2, 16); s2 += __shfl_xor(s2, 32);
        s3 += __shfl_xor(s3, 16); s3 += __shfl_xor(s3, 32);
        s4 += __shfl_xor(s4, 16); s4 += __shfl_xor(s4, 32);
        s5 += __shfl_xor(s5, 16); s5 += __shfl_xor(s5, 32);
        s6 += __shfl_xor(s6, 16); s6 += __shfl_xor(s6, 32);
        s7 += __shfl_xor(s7, 16); s7 += __shfl_xor(s7, 32);
        if (q == 0) {
            float d = (float)(end - beg);
            float inv = (d > 0.f) ? 1.0f / d : 0.0f;
            uint4 o;
            o.x = pk(s0 * inv, s1 * inv);
            o.y = pk(s2 * inv, s3 * inv);
            o.z = pk(s4 * inv, s5 * inv);
            o.w = pk(s6 * inv, s7 * inv);
            hnb4[(size_t)node * 16 + l16] = o;
        }
    }
}

// ===== MFMA GEMM (layer 0), BM=128, 4 waves 2x2, LDS-staged A-tiles =====
// outB = bf16(relu([A0|A1] @ BT^T + b)).  A-tile staged via global_load_lds
// with XOR-swizzled SOURCE (chunk ^= row&7); reads apply the same XOR.

__global__ __launch_bounds__(256, 2) void k_mgemm(
        const unsigned short* __restrict__ A0,
        const unsigned short* __restrict__ A1,
        const unsigned short* __restrict__ BT,
        const float* __restrict__ bias,
        unsigned short* __restrict__ outB) {
    __shared__ char sA[32768];      // 128 rows x 256B
    int t = threadIdx.x;
    int lane = t & 63, wid = t >> 6;
    int wm = wid >> 1, wn = wid & 1;
    int lr = lane & 15, lg = lane >> 4;
    int brow = blockIdx.x * 128;
    int row0 = brow + wm * 64;
    int colw = wn * 64;
    f32x4 zero = {0.f, 0.f, 0.f, 0.f};
    f32x4 acc[4][4];
#pragma unroll
    for (int a = 0; a < 4; ++a)
#pragma unroll
        for (int b = 0; b < 4; ++b) acc[a][b] = zero;

#pragma unroll 1
    for (int p = 0; p < 2; ++p) {
        const unsigned short* A = p ? A1 : A0;
        // ---- async stage: 8 x 1KB per wave, swizzled source chunks ----
#pragma unroll
        for (int it = 0; it < 8; ++it) {
            int rl = wid * 32 + it * 4 + (lane >> 4);
            int ch = (lane & 15) ^ (rl & 7);
            const char* src = (const char*)A + (size_t)(brow + rl) * 256 + ch * 16;
            __builtin_amdgcn_global_load_lds((gas_t)src,
                (las_t)(sA + wid * 8192 + it * 1024), 16, 0, 0);
        }
        __syncthreads();            // drain vmcnt: tile ready
        bf16x8 bReg[4][4];
#pragma unroll
        for (int nf = 0; nf < 4; ++nf)
#pragma unroll
            for (int ks = 0; ks < 4; ++ks)
                bReg[nf][ks] = *(const bf16x8*)&BT[(size_t)(colw + nf * 16 + lr) * 256 + p * 128 + ks * 32 + lg * 8];
#pragma unroll
        for (int mf = 0; mf < 4; ++mf) {
            int rl = wm * 64 + mf * 16 + lr;
            bf16x8 aReg[4];
#pragma unroll
            for (int ks = 0; ks < 4; ++ks)
                aReg[ks] = *(const bf16x8*)&sA[rl * 256 + (((ks * 4 + lg) ^ (rl & 7)) << 4)];
#pragma unroll
            for (int ks = 0; ks < 4; ++ks)
#pragma unroll
                for (int nf = 0; nf < 4; ++nf)
                    acc[mf][nf] = __builtin_amdgcn_mfma_f32_16x16x32_bf16(
                        aReg[ks], bReg[nf][ks], acc[mf][nf], 0, 0, 0);
        }
        __syncthreads();            // all sA reads done before restage / epilogue
    }
    // in-place write (A0 fully consumed during p=0 staging)
#pragma unroll
    for (int nf = 0; nf < 4; ++nf) {
        int cidx = colw + nf * 16 + lr;
        float bb = bias[cidx];
#pragma unroll
        for (int mf = 0; mf < 4; ++mf) {
#pragma unroll
            for (int j = 0; j < 4; ++j) {
                int row = row0 + mf * 16 + lg * 4 + j;
                if (row < NN) {
                    float v = fmaxf(acc[mf][nf][j] + bb, 0.f);
                    outB[(size_t)row * 128 + cidx] = f2bf(v);
                }
            }
        }
    }
}

// ========= fused layer 1 + layer 2 transform, LDS-staged =========
// Phase A: h2 = relu([A0|A1]@BT1^T + b1) -> padded LDS tile + outB (in-place)
// Phase B: S = h2@Ws2+b2 (fp32, stride 48), TB = h2@Wn2 (bf16, stride-64 rows)
// Shared buffer reused: [0,32768) = staging (swizzled chunks), then h2 tile
// in padded [128][132] u16 layout (R16-proven, conflict-free).

__global__ __launch_bounds__(256, 2) void k_mgemm_l12(
        const unsigned short* __restrict__ A0,
        const unsigned short* __restrict__ A1,
        const unsigned short* __restrict__ BT,
        const float* __restrict__ bias,
        unsigned short* __restrict__ outB,        // = A0
        const unsigned short* __restrict__ BT2,   // [96][128]
        const float* __restrict__ bias2,
        float* __restrict__ S,
        unsigned short* __restrict__ TB) {
    __shared__ char buf[33792];                   // staging (32KB) then hl[128][132]
    unsigned short* hl = (unsigned short*)buf;
    int t = threadIdx.x;
    int lane = t & 63, wid = t >> 6;
    int wm = wid >> 1, wn = wid & 1;
    int lr = lane & 15, lg = lane >> 4;
    int brow = blockIdx.x * 128;
    int row0 = brow + wm * 64;
    int colw = wn * 64;
    f32x4 zero = {0.f, 0.f, 0.f, 0.f};
    f32x4 acc[4][4];
#pragma unroll
    for (int a = 0; a < 4; ++a)
#pragma unroll
        for (int b = 0; b < 4; ++b) acc[a][b] = zero;

#pragma unroll 1
    for (int p = 0; p < 2; ++p) {
        const unsigned short* A = p ? A1 : A0;
#pragma unroll
        for (int it = 0; it < 8; ++it) {
            int rl = wid * 32 + it * 4 + (lane >> 4);
            int ch = (lane & 15) ^ (rl & 7);
            const char* src = (const char*)A + (size_t)(brow + rl) * 256 + ch * 16;
            __builtin_amdgcn_global_load_lds((gas_t)src,
                (las_t)(buf + wid * 8192 + it * 1024), 16, 0, 0);
        }
        __syncthreads();
        bf16x8 bReg[4][4];
#pragma unroll
        for (int nf = 0; nf < 4; ++nf)
#pragma unroll
            for (int ks = 0; ks < 4; ++ks)
                bReg[nf][ks] = *(const bf16x8*)&BT[(size_t)(colw + nf * 16 + lr) * 256 + p * 128 + ks * 32 + lg * 8];
#pragma unroll
        for (int mf = 0; mf < 4; ++mf) {
            int rl = wm * 64 + mf * 16 + lr;
            bf16x8 aReg[4];
#pragma unroll
            for (int ks = 0; ks < 4; ++ks)
                aReg[ks] = *(const bf16x8*)&buf[rl * 256 + (((ks * 4 + lg) ^ (rl & 7)) << 4)];
#pragma unroll
            for (int ks = 0; ks < 4; ++ks)
#pragma unroll
                for (int nf = 0; nf < 4; ++nf)
                    acc[mf][nf] = __builtin_amdgcn_mfma_f32_16x16x32_bf16(
                        aReg[ks], bReg[nf][ks], acc[mf][nf], 0, 0, 0);
        }
        __syncthreads();            // staging buffer dead after p=1
    }
    // h2: padded LDS tile (conflict-free) + global in-place over A0
#pragma unroll
    for (int nf = 0; nf < 4; ++nf) {
        int cidx = colw + nf * 16 + lr;
        float bb = bias[cidx];
#pragma unroll
        for (int mf = 0; mf < 4; ++mf) {
#pragma unroll
            for (int j = 0; j < 4; ++j) {
                int lrow = wm * 64 + mf * 16 + lg * 4 + j;
                float v = fmaxf(acc[mf][nf][j] + bb, 0.f);
                unsigned short bv = f2bf(v);
                hl[lrow * 132 + cidx] = bv;
                acc[mf][nf][j] = __uint_as_float((unsigned int)bv);
            }
        }
    }
    __syncthreads();                // h2 tile complete
    // global h2 write (in-place over A0)
#pragma unroll
    for (int nf = 0; nf < 4; ++nf) {
        int cidx = colw + nf * 16 + lr;
#pragma unroll
        for (int mf = 0; mf < 4; ++mf) {
#pragma unroll
            for (int j = 0; j < 4; ++j) {
                int row = row0 + mf * 16 + lg * 4 + j;
                if (row < NN)
                    outB[(size_t)row * 128 + cidx] =
                        (unsigned short)__float_as_uint(acc[mf][nf][j]);
            }
        }
    }
    // phase B: S/T from padded hl
    int colw2 = wn * 48;
    f32x4 acc2[4][3];
#pragma unroll
    for (int a = 0; a < 4; ++a)
#pragma unroll
        for (int b = 0; b < 3; ++b) acc2[a][b] = zero;
    bf16x8 bReg2[3][4];
#pragma unroll
    for (int nf = 0; nf < 3; ++nf)
#pragma unroll
        for (int ks = 0; ks < 4; ++ks)
            bReg2[nf][ks] = *(const bf16x8*)&BT2[(size_t)(colw2 + nf * 16 + lr) * 128 + ks * 32 + lg * 8];
#pragma unroll
    for (int mf = 0; mf < 4; ++mf) {
        int rl = wm * 64 + mf * 16 + lr;
        bf16x8 aReg[4];
#pragma unroll
        for (int ks = 0; ks < 4; ++ks)
            aReg[ks] = *(const bf16x8*)&hl[rl * 132 + ks * 32 + lg * 8];
#pragma unroll
        for (int ks = 0; ks < 4; ++ks)
#pragma unroll
            for (int nf = 0; nf < 3; ++nf)
                acc2[mf][nf] = __builtin_amdgcn_mfma_f32_16x16x32_bf16(
                    aReg[ks], bReg2[nf][ks], acc2[mf][nf], 0, 0, 0);
    }
#pragma unroll
    for (int nf = 0; nf < 3; ++nf) {
        int cidx = colw2 + nf * 16 + lr;     // 0..95
#pragma unroll
        for (int mf = 0; mf < 4; ++mf) {
#pragma unroll
            for (int j = 0; j < 4; ++j) {
                int row = brow + wm * 64 + mf * 16 + lg * 4 + j;
                if (row < NN) {
                    float v = acc2[mf][nf][j];
                    if (cidx < 47)
                        S[(size_t)row * 48 + cidx] = v + bias2[cidx];
                    else if (cidx >= 48)
                        TB[(size_t)row * 64 + (cidx - 48)] = f2bf(v);
                }
            }
        }
    }
}

// ======== layer-2 aggregate: out = S + mean(TB), quarter-wave uint2 (full 128B row) ========

__global__ __launch_bounds__(256) void k_gather47(
        const uint2* __restrict__ TB2,   // [node][16] uint2 (128B padded bf16 rows)
        const float4* __restrict__ S4,   // [node][12] float4 (48 fp32)
        const int* __restrict__ rp, const int* __restrict__ col,
        float* __restrict__ out) {
    int wave = blockIdx.x * 4 + (threadIdx.x >> 6);
    int lane = threadIdx.x & 63;
    int q = lane >> 4, l16 = lane & 15;
    int n0 = wave * NPW;
    int n1 = min(n0 + NPW, NN);
    for (int node = n0; node < n1; ++node) {
        int beg = rp[node], end = rp[node + 1];
        float a0 = 0.f, a1 = 0.f, a2 = 0.f, a3 = 0.f;
        float b0 = 0.f, b1 = 0.f, b2 = 0.f, b3 = 0.f;
        int e = beg;
        for (; e + 8 <= end; e += 8) {
            int i0 = col[e + q];
            int i1 = col[e + 4 + q];
            uint2 u0 = TB2[(size_t)i0 * 16 + l16];
            uint2 u1 = TB2[(size_t)i1 * 16 + l16];
            a0 += lo16(u0.x); a1 += hi16(u0.x); a2 += lo16(u0.y); a3 += hi16(u0.y);
            b0 += lo16(u1.x); b1 += hi16(u1.x); b2 += lo16(u1.y); b3 += hi16(u1.y);
        }
        for (; e < end; e += 4) {
            if (e + q < end) {
                uint2 u = TB2[(size_t)col[e + q] * 16 + l16];
                a0 += lo16(u.x); a1 += hi16(u.x); a2 += lo16(u.y); a3 += hi16(u.y);
            }
        }
        float s0 = a0 + b0, s1 = a1 + b1, s2 = a2 + b2, s3 = a3 + b3;
        s0 += __shfl_xor(s0, 16); s0 += __shfl_xor(s0, 32);
        s1 += __shfl_xor(s1, 16); s1 += __shfl_xor(s1, 32);
        s2 += __shfl_xor(s2, 16); s2 += __shfl_xor(s2, 32);
        s3 += __shfl_xor(s3, 16); s3 += __shfl_xor(s3, 32);
        if (q == 0 && l16 < 12) {
            float d = (float)(end - beg);
            float inv = (d > 0.f) ? 1.0f / d : 0.0f;
            float4 sv = S4[(size_t)node * 12 + l16];
            int c = l16 * 4;
            out[(size_t)node * 47 + c]     = sv.x + s0 * inv;
            out[(size_t)node * 47 + c + 1] = sv.y + s1 * inv;
            out[(size_t)node * 47 + c + 2] = sv.z + s2 * inv;
            if (c + 3 < 47) out[(size_t)node * 47 + c + 3] = sv.w + s3 * inv;
        }
    }
}

// ================= launcher =================

static inline size_t align_up(size_t x, size_t a) { return (x + a - 1) / a * a; }

extern "C" void kernel_launch(void* const* d_in, const int* in_sizes, int n_in,
                              void* d_out, int out_size, void* d_ws, size_t ws_size,
                              hipStream_t stream) {
    const float* x   = (const float*)d_in[0];
    const int* src   = (const int*)d_in[1];
    const int* dst   = (const int*)d_in[2];
    const float* Ws0 = (const float*)d_in[3];
    const float* Wn0 = (const float*)d_in[4];
    const float* b0  = (const float*)d_in[5];
    const float* Ws1 = (const float*)d_in[6];
    const float* Wn1 = (const float*)d_in[7];
    const float* b1  = (const float*)d_in[8];
    const float* Ws2 = (const float*)d_in[9];
    const float* Wn2 = (const float*)d_in[10];
    const float* b2  = (const float*)d_in[11];
    float* out = (float*)d_out;

    char* ws = (char*)d_ws;
    size_t off = 0;
    auto alloc = [&](size_t bytes) -> void* {
        void* p = ws + off; off = align_up(off + bytes, 256); return p;
    };
    int* row_ptr = (int*)alloc((size_t)(NN + 1) * 4);
    int* boff    = (int*)alloc((size_t)(NBK + 1) * 4);
    int* gbase   = (int*)alloc((size_t)NBLK * NBK * 4);
    int* ghist   = (int*)alloc((size_t)NBLK * NBK * 4);
    int* col     = (int*)alloc((size_t)NE * 4);
    unsigned short* XB  = (unsigned short*)alloc((size_t)MPAD * 128 * 2);   // 25.6MB
    unsigned short* BT0 = (unsigned short*)alloc(128 * 256 * 2);
    unsigned short* BT1 = (unsigned short*)alloc(128 * 256 * 2);
    unsigned short* BT2 = (unsigned short*)alloc(96 * 128 * 2);
    unsigned int* HNB   = (unsigned int*)alloc((size_t)MPAD * 128 * 2);     // 25.6MB (gather out)
    // S+TB region; eb (CSR build, 6.4MB) time-shares its head (dead before S/TB written)
    size_t sbytes  = (size_t)NN * 48 * 4;          // 19.2MB fp32 S
    size_t tbbytes = (size_t)MPAD * 64 * 2;        // 12.8MB bf16 TB (128B rows)
    char* stb = (char*)alloc(sbytes + tbbytes);
    unsigned int* eb   = (unsigned int*)stb;
    float* S           = (float*)stb;
    unsigned short* TB = (unsigned short*)(stb + sbytes);

    // --- CSR build + prep (hist launch also does cast + weight transposes) ---
    k_hist_prep<<<NBLK + PREPB, 256, 0, stream>>>(
        dst, ghist, (const float4*)x, (ushort4*)XB,
        Ws0, Wn0, BT0, Ws1, Wn1, BT1, Ws2, Wn2, BT2);
    k_basescan<<<1, 512, 0, stream>>>(ghist, boff, gbase);
    k_scatter<<<NBLK, 256, 0, stream>>>(src, dst, gbase, eb);
    k_csr<<<NBK, 256, 0, stream>>>(eb, boff, row_ptr, col);

    int mgrid = MPAD / 128;   // 782

    // --- layer 0 (bf16 in-place over XB) ---
    k_gather128<<<GBLK, 256, 0, stream>>>((const uint4*)XB, row_ptr, col, (uint4*)HNB);
    k_mgemm<<<mgrid, 256, 0, stream>>>(XB, (const unsigned short*)HNB, BT0, b0, XB);
    // --- layer 1 + layer-2 transform (fused; h2 in-place over XB, S/TB out) ---
    k_gather128<<<GBLK, 256, 0, stream>>>((const uint4*)XB, row_ptr, col, (uint4*)HNB);
    k_mgemm_l12<<<mgrid, 256, 0, stream>>>(XB, (const unsigned short*)HNB, BT1, b1, XB,
                                           BT2, b2, S, TB);
    // --- layer 2 aggregate ---
    k_gather47<<<GBLK, 256, 0, stream>>>((const uint2*)TB, (const float4*)S,
                                         row_ptr, col, out);
}

// Round 20
// 314.244 us; speedup vs baseline: 1.1108x; 1.0592x over previous
//
#include <hip/hip_runtime.h>

#define NN 100000
#define NE 1600000
#define NBK 391                     // buckets of 256 dst nodes
#define CHUNK 8192
#define NBLK ((NE + CHUNK - 1) / CHUNK)   // 196
#define MPAD 100096                 // NN padded to multiple of 128
#define CASTB 12500                 // (NN*128/4) float4 / 256 threads
#define PREPB (CASTB + 128 + 128 + 48)    // 12804
#define GBLK 2048                   // gather blocks (8192 waves)
#define NPW ((NN + 8191) / 8192)    // nodes per wave = 13

using bf16x8 = __attribute__((ext_vector_type(8))) short;
using f32x4  = __attribute__((ext_vector_type(4))) float;

typedef const __attribute__((address_space(1))) unsigned int* gas_t;
typedef __attribute__((address_space(3))) unsigned int* las_t;

static __device__ __forceinline__ unsigned short f2bf(float f) {
    unsigned int u = __float_as_uint(f);
    unsigned int r = (u + 0x7FFFu + ((u >> 16) & 1u)) >> 16;   // RNE
    return (unsigned short)r;
}
static __device__ __forceinline__ float lo16(unsigned int u) {
    return __uint_as_float(u << 16);
}
static __device__ __forceinline__ float hi16(unsigned int u) {
    return __uint_as_float(u & 0xFFFF0000u);
}
static __device__ __forceinline__ unsigned int pk(float lo, float hi) {
    return ((unsigned int)f2bf(hi) << 16) | (unsigned int)f2bf(lo);
}

// ============ CSR hist + all prep work in one launch ============

__global__ __launch_bounds__(256) void k_hist_prep(
        const int* __restrict__ dst, int* __restrict__ ghist,
        const float4* __restrict__ x4, ushort4* __restrict__ XB4,
        const float* __restrict__ Ws0, const float* __restrict__ Wn0,
        unsigned short* __restrict__ BT0,
        const float* __restrict__ Ws1, const float* __restrict__ Wn1,
        unsigned short* __restrict__ BT1,
        const float* __restrict__ Ws2, const float* __restrict__ Wn2,
        unsigned short* __restrict__ BT2) {
    __shared__ int h[NBK];
    int bid = blockIdx.x, t = threadIdx.x;
    if (bid < NBLK) {
        for (int i = t; i < NBK; i += 256) h[i] = 0;
        __syncthreads();
        int beg = bid * CHUNK, end = min(beg + CHUNK, NE);
        for (int i = beg + t; i < end; i += 256)
            atomicAdd(&h[dst[i] >> 8], 1);
        __syncthreads();
        for (int i = t; i < NBK; i += 256) ghist[bid * NBK + i] = h[i];
        return;
    }
    int pb = bid - NBLK;
    if (pb < CASTB) {
        int i = pb * 256 + t;
        float4 v = x4[i];
        ushort4 o;
        o.x = f2bf(v.x); o.y = f2bf(v.y); o.z = f2bf(v.z); o.w = f2bf(v.w);
        XB4[i] = o;
    } else if (pb < CASTB + 128) {
        int idx = (pb - CASTB) * 256 + t;
        int k = idx >> 7, n = idx & 127;
        float v = (k < 128) ? Ws0[k * 128 + n] : Wn0[(k - 128) * 128 + n];
        BT0[n * 256 + k] = f2bf(v);
    } else if (pb < CASTB + 256) {
        int idx = (pb - CASTB - 128) * 256 + t;
        int k = idx >> 7, n = idx & 127;
        float v = (k < 128) ? Ws1[k * 128 + n] : Wn1[(k - 128) * 128 + n];
        BT1[n * 256 + k] = f2bf(v);
    } else {
        int idx = (pb - CASTB - 256) * 256 + t;
        if (idx < 96 * 128) {
            int n = idx >> 7, k = idx & 127;
            float v = 0.f;
            if (n < 48) { if (n < 47) v = Ws2[k * 47 + n]; }
            else        { int cc = n - 48; if (cc < 47) v = Wn2[k * 47 + cc]; }
            BT2[n * 128 + k] = f2bf(v);
        }
    }
}

// single block: bucket totals -> boff (exclusive), per-(block,bucket) bases
__global__ __launch_bounds__(512) void k_basescan(const int* __restrict__ ghist,
                                                  int* __restrict__ boff,
                                                  int* __restrict__ gbase) {
    __shared__ int s[512];
    int t = threadIdx.x;
    int tot = 0;
    if (t < NBK) {
#pragma unroll 4
        for (int blk = 0; blk < NBLK; ++blk) tot += ghist[blk * NBK + t];
    }
    s[t] = tot;
    __syncthreads();
    for (int o = 1; o < 512; o <<= 1) {
        int u = (t >= o) ? s[t - o] : 0;
        __syncthreads();
        s[t] += u;
        __syncthreads();
    }
    int base = s[t] - tot;
    if (t <= NBK) boff[t] = base;
    if (t < NBK) {
        int run = base;
        for (int blk = 0; blk < NBLK; ++blk) {
            int g = ghist[blk * NBK + t];
            gbase[blk * NBK + t] = run;
            run += g;
        }
    }
}

__global__ __launch_bounds__(256) void k_scatter(const int* __restrict__ src,
                                                 const int* __restrict__ dst,
                                                 const int* __restrict__ gbase,
                                                 unsigned int* __restrict__ eb) {
    __shared__ int cur[NBK];
    int b = blockIdx.x, t = threadIdx.x;
    for (int i = t; i < NBK; i += 256) cur[i] = gbase[b * NBK + i];
    __syncthreads();
    int beg = b * CHUNK, end = min(beg + CHUNK, NE);
    for (int i = beg + t; i < end; i += 256) {
        int d = dst[i];
        int p = atomicAdd(&cur[d >> 8], 1);
        eb[p] = ((unsigned int)(d & 255) << 24) | (unsigned int)src[i];
    }
}

// fused: per-bucket degree hist -> LDS scan -> row_ptr -> col fill
__global__ __launch_bounds__(256) void k_csr(const unsigned int* __restrict__ eb,
                                             const int* __restrict__ boff,
                                             int* __restrict__ rp,
                                             int* __restrict__ col) {
    __shared__ int h[256];
    __shared__ int sc[256];
    __shared__ int cur[256];
    int b = blockIdx.x, t = threadIdx.x;
    h[t] = 0;
    __syncthreads();
    int beg = boff[b], end = boff[b + 1];
    for (int e = beg + t; e < end; e += 256)
        atomicAdd(&h[eb[e] >> 24], 1);
    __syncthreads();
    int c = h[t];
    sc[t] = c;
    __syncthreads();
    for (int o = 1; o < 256; o <<= 1) {
        int v = (t >= o) ? sc[t - o] : 0;
        __syncthreads();
        sc[t] += v;
        __syncthreads();
    }
    int excl = beg + sc[t] - c;
    int node = (b << 8) + t;
    if (node < NN) rp[node] = excl;
    if (node == NN - 1) rp[NN] = NE;
    cur[t] = excl;
    __syncthreads();
    for (int e = beg + t; e < end; e += 256) {
        unsigned int p = eb[e];
        int pos = atomicAdd(&cur[p >> 24], 1);
        col[pos] = (int)(p & 0xFFFFFFu);
    }
}

// ======== mean-aggregate gather 128-feat: quarter-wave uint4, 4 edges/instr ========

__global__ __launch_bounds__(256) void k_gather128(
        const uint4* __restrict__ hb4,   // [node][16] uint4 (256B bf16 rows)
        const int* __restrict__ rp, const int* __restrict__ col,
        uint4* __restrict__ hnb4) {
    int wave = blockIdx.x * 4 + (threadIdx.x >> 6);
    int lane = threadIdx.x & 63;
    int q = lane >> 4, l16 = lane & 15;
    int n0 = wave * NPW;
    int n1 = min(n0 + NPW, NN);
    for (int node = n0; node < n1; ++node) {
        int beg = rp[node], end = rp[node + 1];
        float a0 = 0.f, a1 = 0.f, a2 = 0.f, a3 = 0.f;
        float a4 = 0.f, a5 = 0.f, a6 = 0.f, a7 = 0.f;
        float b0 = 0.f, b1 = 0.f, b2 = 0.f, b3 = 0.f;
        float b4 = 0.f, b5 = 0.f, b6 = 0.f, b7 = 0.f;
        int e = beg;
        for (; e + 8 <= end; e += 8) {
            int c0 = col[e + q];
            int c1 = col[e + 4 + q];
            uint4 v0 = hb4[(size_t)c0 * 16 + l16];
            uint4 v1 = hb4[(size_t)c1 * 16 + l16];
            a0 += lo16(v0.x); a1 += hi16(v0.x); a2 += lo16(v0.y); a3 += hi16(v0.y);
            a4 += lo16(v0.z); a5 += hi16(v0.z); a6 += lo16(v0.w); a7 += hi16(v0.w);
            b0 += lo16(v1.x); b1 += hi16(v1.x); b2 += lo16(v1.y); b3 += hi16(v1.y);
            b4 += lo16(v1.z); b5 += hi16(v1.z); b6 += lo16(v1.w); b7 += hi16(v1.w);
        }
        for (; e < end; e += 4) {
            if (e + q < end) {
                uint4 v = hb4[(size_t)col[e + q] * 16 + l16];
                a0 += lo16(v.x); a1 += hi16(v.x); a2 += lo16(v.y); a3 += hi16(v.y);
                a4 += lo16(v.z); a5 += hi16(v.z); a6 += lo16(v.w); a7 += hi16(v.w);
            }
        }
        float s0 = a0 + b0, s1 = a1 + b1, s2 = a2 + b2, s3 = a3 + b3;
        float s4 = a4 + b4, s5 = a5 + b5, s6 = a6 + b6, s7 = a7 + b7;
        s0 += __shfl_xor(s0, 16); s0 += __shfl_xor(s0, 32);
        s1 += __shfl_xor(s1, 16); s1 += __shfl_xor(s1, 32);
        s2 += __shfl_xor(s2, 16); s2 += __shfl_xor(s2, 32);
        s3 += __shfl_xor(s3, 16); s3 += __shfl_xor(s3, 32);
        s4 += __shfl_xor(s4, 16); s4 += __shfl_xor(s4, 32);
        s5 += __shfl_xor(s5, 16); s5 += __shfl_xor(s5, 32);
        s6 += __shfl_xor(s6, 16); s6 += __shfl_xor(s6, 32);
        s7 += __shfl_xor(s7, 16); s7 += __shfl_xor(s7, 32);
        if (q == 0) {
            float d = (float)(end - beg);
            float inv = (d > 0.f) ? 1.0f / d : 0.0f;
            uint4 o;
            o.x = pk(s0 * inv, s1 * inv);
            o.y = pk(s2 * inv, s3 * inv);
            o.z = pk(s4 * inv, s5 * inv);
            o.w = pk(s6 * inv, s7 * inv);
            hnb4[(size_t)node * 16 + l16] = o;
        }
    }
}

// ===== MFMA GEMM (layer 0), BM=128, 4 waves 2x2, LDS-staged A-tiles =====
// outB = bf16(relu([A0|A1] @ BT^T + b)).  A-tile staged via global_load_lds
// (swizzled source chunks); epilogue bounces the bf16 tile through LDS
// (padded [128][136]) for fully coalesced uint4 global stores.

__global__ __launch_bounds__(256, 2) void k_mgemm(
        const unsigned short* __restrict__ A0,
        const unsigned short* __restrict__ A1,
        const unsigned short* __restrict__ BT,
        const float* __restrict__ bias,
        unsigned short* __restrict__ outB) {
    __shared__ char sA[34816];      // staging (32KB) then hl[128][136] u16
    unsigned short* hl = (unsigned short*)sA;
    int t = threadIdx.x;
    int lane = t & 63, wid = t >> 6;
    int wm = wid >> 1, wn = wid & 1;
    int lr = lane & 15, lg = lane >> 4;
    int brow = blockIdx.x * 128;
    int colw = wn * 64;
    f32x4 zero = {0.f, 0.f, 0.f, 0.f};
    f32x4 acc[4][4];
#pragma unroll
    for (int a = 0; a < 4; ++a)
#pragma unroll
        for (int b = 0; b < 4; ++b) acc[a][b] = zero;

#pragma unroll 1
    for (int p = 0; p < 2; ++p) {
        const unsigned short* A = p ? A1 : A0;
#pragma unroll
        for (int it = 0; it < 8; ++it) {
            int rl = wid * 32 + it * 4 + (lane >> 4);
            int ch = (lane & 15) ^ (rl & 7);
            const char* src = (const char*)A + (size_t)(brow + rl) * 256 + ch * 16;
            __builtin_amdgcn_global_load_lds((gas_t)src,
                (las_t)(sA + wid * 8192 + it * 1024), 16, 0, 0);
        }
        __syncthreads();            // drain vmcnt: tile ready
        bf16x8 bReg[4][4];
#pragma unroll
        for (int nf = 0; nf < 4; ++nf)
#pragma unroll
            for (int ks = 0; ks < 4; ++ks)
                bReg[nf][ks] = *(const bf16x8*)&BT[(size_t)(colw + nf * 16 + lr) * 256 + p * 128 + ks * 32 + lg * 8];
#pragma unroll
        for (int mf = 0; mf < 4; ++mf) {
            int rl = wm * 64 + mf * 16 + lr;
            bf16x8 aReg[4];
#pragma unroll
            for (int ks = 0; ks < 4; ++ks)
                aReg[ks] = *(const bf16x8*)&sA[rl * 256 + (((ks * 4 + lg) ^ (rl & 7)) << 4)];
#pragma unroll
            for (int ks = 0; ks < 4; ++ks)
#pragma unroll
                for (int nf = 0; nf < 4; ++nf)
                    acc[mf][nf] = __builtin_amdgcn_mfma_f32_16x16x32_bf16(
                        aReg[ks], bReg[nf][ks], acc[mf][nf], 0, 0, 0);
        }
        __syncthreads();            // sA reads done before restage / epilogue
    }
    // epilogue: relu+bias -> padded LDS tile -> coalesced uint4 stores
#pragma unroll
    for (int nf = 0; nf < 4; ++nf) {
        int cidx = colw + nf * 16 + lr;
        float bb = bias[cidx];
#pragma unroll
        for (int mf = 0; mf < 4; ++mf) {
#pragma unroll
            for (int j = 0; j < 4; ++j) {
                int lrow = wm * 64 + mf * 16 + lg * 4 + j;
                hl[lrow * 136 + cidx] = f2bf(fmaxf(acc[mf][nf][j] + bb, 0.f));
            }
        }
    }
    __syncthreads();
    uint4* ob4 = (uint4*)outB;
#pragma unroll
    for (int i = 0; i < 8; ++i) {
        int idx = i * 256 + t;          // 2048 uint4 = 128 rows x 16
        int row = idx >> 4, c = idx & 15;
        uint4 val = *(const uint4*)&hl[row * 136 + c * 8];
        ob4[(size_t)(brow + row) * 16 + c] = val;   // padding rows harmless
    }
}

// ========= fused layer 1 + layer 2 transform, LDS-staged =========
// Phase A: h2 = relu([A0|A1]@BT1^T + b1) -> padded LDS tile -> coalesced outB
// Phase B: S = h2@Ws2+b2 (fp32, stride 48), TB = h2@Wn2 (bf16, stride-64 rows)

__global__ __launch_bounds__(256, 2) void k_mgemm_l12(
        const unsigned short* __restrict__ A0,
        const unsigned short* __restrict__ A1,
        const unsigned short* __restrict__ BT,
        const float* __restrict__ bias,
        unsigned short* __restrict__ outB,        // = A0
        const unsigned short* __restrict__ BT2,   // [96][128]
        const float* __restrict__ bias2,
        float* __restrict__ S,
        unsigned short* __restrict__ TB) {
    __shared__ char buf[34816];                   // staging (32KB) then hl[128][136]
    unsigned short* hl = (unsigned short*)buf;
    int t = threadIdx.x;
    int lane = t & 63, wid = t >> 6;
    int wm = wid >> 1, wn = wid & 1;
    int lr = lane & 15, lg = lane >> 4;
    int brow = blockIdx.x * 128;
    int colw = wn * 64;
    f32x4 zero = {0.f, 0.f, 0.f, 0.f};
    f32x4 acc[4][4];
#pragma unroll
    for (int a = 0; a < 4; ++a)
#pragma unroll
        for (int b = 0; b < 4; ++b) acc[a][b] = zero;

#pragma unroll 1
    for (int p = 0; p < 2; ++p) {
        const unsigned short* A = p ? A1 : A0;
#pragma unroll
        for (int it = 0; it < 8; ++it) {
            int rl = wid * 32 + it * 4 + (lane >> 4);
            int ch = (lane & 15) ^ (rl & 7);
            const char* src = (const char*)A + (size_t)(brow + rl) * 256 + ch * 16;
            __builtin_amdgcn_global_load_lds((gas_t)src,
                (las_t)(buf + wid * 8192 + it * 1024), 16, 0, 0);
        }
        __syncthreads();
        bf16x8 bReg[4][4];
#pragma unroll
        for (int nf = 0; nf < 4; ++nf)
#pragma unroll
            for (int ks = 0; ks < 4; ++ks)
                bReg[nf][ks] = *(const bf16x8*)&BT[(size_t)(colw + nf * 16 + lr) * 256 + p * 128 + ks * 32 + lg * 8];
#pragma unroll
        for (int mf = 0; mf < 4; ++mf) {
            int rl = wm * 64 + mf * 16 + lr;
            bf16x8 aReg[4];
#pragma unroll
            for (int ks = 0; ks < 4; ++ks)
                aReg[ks] = *(const bf16x8*)&buf[rl * 256 + (((ks * 4 + lg) ^ (rl & 7)) << 4)];
#pragma unroll
            for (int ks = 0; ks < 4; ++ks)
#pragma unroll
                for (int nf = 0; nf < 4; ++nf)
                    acc[mf][nf] = __builtin_amdgcn_mfma_f32_16x16x32_bf16(
                        aReg[ks], bReg[nf][ks], acc[mf][nf], 0, 0, 0);
        }
        __syncthreads();            // staging buffer dead after p=1
    }
    // h2 -> padded LDS tile
#pragma unroll
    for (int nf = 0; nf < 4; ++nf) {
        int cidx = colw + nf * 16 + lr;
        float bb = bias[cidx];
#pragma unroll
        for (int mf = 0; mf < 4; ++mf) {
#pragma unroll
            for (int j = 0; j < 4; ++j) {
                int lrow = wm * 64 + mf * 16 + lg * 4 + j;
                hl[lrow * 136 + cidx] = f2bf(fmaxf(acc[mf][nf][j] + bb, 0.f));
            }
        }
    }
    __syncthreads();                // h2 tile complete
    // coalesced global h2 write (in-place over A0; padding rows harmless)
    uint4* ob4 = (uint4*)outB;
#pragma unroll
    for (int i = 0; i < 8; ++i) {
        int idx = i * 256 + t;
        int row = idx >> 4, c = idx & 15;
        uint4 val = *(const uint4*)&hl[row * 136 + c * 8];
        ob4[(size_t)(brow + row) * 16 + c] = val;
    }
    // phase B: S/T from padded hl
    int colw2 = wn * 48;
    f32x4 acc2[4][3];
#pragma unroll
    for (int a = 0; a < 4; ++a)
#pragma unroll
        for (int b = 0; b < 3; ++b) acc2[a][b] = zero;
    bf16x8 bReg2[3][4];
#pragma unroll
    for (int nf = 0; nf < 3; ++nf)
#pragma unroll
        for (int ks = 0; ks < 4; ++ks)
            bReg2[nf][ks] = *(const bf16x8*)&BT2[(size_t)(colw2 + nf * 16 + lr) * 128 + ks * 32 + lg * 8];
#pragma unroll
    for (int mf = 0; mf < 4; ++mf) {
        int rl = wm * 64 + mf * 16 + lr;
        bf16x8 aReg[4];
#pragma unroll
        for (int ks = 0; ks < 4; ++ks)
            aReg[ks] = *(const bf16x8*)&hl[rl * 136 + ks * 32 + lg * 8];
#pragma unroll
        for (int ks = 0; ks < 4; ++ks)
#pragma unroll
            for (int nf = 0; nf < 3; ++nf)
                acc2[mf][nf] = __builtin_amdgcn_mfma_f32_16x16x32_bf16(
                    aReg[ks], bReg2[nf][ks], acc2[mf][nf], 0, 0, 0);
    }
#pragma unroll
    for (int nf = 0; nf < 3; ++nf) {
        int cidx = colw2 + nf * 16 + lr;     // 0..95
#pragma unroll
        for (int mf = 0; mf < 4; ++mf) {
#pragma unroll
            for (int j = 0; j < 4; ++j) {
                int row = brow + wm * 64 + mf * 16 + lg * 4 + j;
                if (row < NN) {
                    float v = acc2[mf][nf][j];
                    if (cidx < 47)
                        S[(size_t)row * 48 + cidx] = v + bias2[cidx];
                    else if (cidx >= 48)
                        TB[(size_t)row * 64 + (cidx - 48)] = f2bf(v);
                }
            }
        }
    }
}

// ======== layer-2 aggregate: out = S + mean(TB), quarter-wave uint2 (full 128B row) ========

__global__ __launch_bounds__(256) void k_gather47(
        const uint2* __restrict__ TB2,   // [node][16] uint2 (128B padded bf16 rows)
        const float4* __restrict__ S4,   // [node][12] float4 (48 fp32)
        const int* __restrict__ rp, const int* __restrict__ col,
        float* __restrict__ out) {
    int wave = blockIdx.x * 4 + (threadIdx.x >> 6);
    int lane = threadIdx.x & 63;
    int q = lane >> 4, l16 = lane & 15;
    int n0 = wave * NPW;
    int n1 = min(n0 + NPW, NN);
    for (int node = n0; node < n1; ++node) {
        int beg = rp[node], end = rp[node + 1];
        float a0 = 0.f, a1 = 0.f, a2 = 0.f, a3 = 0.f;
        float b0 = 0.f, b1 = 0.f, b2 = 0.f, b3 = 0.f;
        int e = beg;
        for (; e + 8 <= end; e += 8) {
            int i0 = col[e + q];
            int i1 = col[e + 4 + q];
            uint2 u0 = TB2[(size_t)i0 * 16 + l16];
            uint2 u1 = TB2[(size_t)i1 * 16 + l16];
            a0 += lo16(u0.x); a1 += hi16(u0.x); a2 += lo16(u0.y); a3 += hi16(u0.y);
            b0 += lo16(u1.x); b1 += hi16(u1.x); b2 += lo16(u1.y); b3 += hi16(u1.y);
        }
        for (; e < end; e += 4) {
            if (e + q < end) {
                uint2 u = TB2[(size_t)col[e + q] * 16 + l16];
                a0 += lo16(u.x); a1 += hi16(u.x); a2 += lo16(u.y); a3 += hi16(u.y);
            }
        }
        float s0 = a0 + b0, s1 = a1 + b1, s2 = a2 + b2, s3 = a3 + b3;
        s0 += __shfl_xor(s0, 16); s0 += __shfl_xor(s0, 32);
        s1 += __shfl_xor(s1, 16); s1 += __shfl_xor(s1, 32);
        s2 += __shfl_xor(s2, 16); s2 += __shfl_xor(s2, 32);
        s3 += __shfl_xor(s3, 16); s3 += __shfl_xor(s3, 32);
        if (q == 0 && l16 < 12) {
            float d = (float)(end - beg);
            float inv = (d > 0.f) ? 1.0f / d : 0.0f;
            float4 sv = S4[(size_t)node * 12 + l16];
            int c = l16 * 4;
            out[(size_t)node * 47 + c]     = sv.x + s0 * inv;
            out[(size_t)node * 47 + c + 1] = sv.y + s1 * inv;
            out[(size_t)node * 47 + c + 2] = sv.z + s2 * inv;
            if (c + 3 < 47) out[(size_t)node * 47 + c + 3] = sv.w + s3 * inv;
        }
    }
}

// ================= launcher =================

static inline size_t align_up(size_t x, size_t a) { return (x + a - 1) / a * a; }

extern "C" void kernel_launch(void* const* d_in, const int* in_sizes, int n_in,
                              void* d_out, int out_size, void* d_ws, size_t ws_size,
                              hipStream_t stream) {
    const float* x   = (const float*)d_in[0];
    const int* src   = (const int*)d_in[1];
    const int* dst   = (const int*)d_in[2];
    const float* Ws0 = (const float*)d_in[3];
    const float* Wn0 = (const float*)d_in[4];
    const float* b0  = (const float*)d_in[5];
    const float* Ws1 = (const float*)d_in[6];
    const float* Wn1 = (const float*)d_in[7];
    const float* b1  = (const float*)d_in[8];
    const float* Ws2 = (const float*)d_in[9];
    const float* Wn2 = (const float*)d_in[10];
    const float* b2  = (const float*)d_in[11];
    float* out = (float*)d_out;

    char* ws = (char*)d_ws;
    size_t off = 0;
    auto alloc = [&](size_t bytes) -> void* {
        void* p = ws + off; off = align_up(off + bytes, 256); return p;
    };
    int* row_ptr = (int*)alloc((size_t)(NN + 1) * 4);
    int* boff    = (int*)alloc((size_t)(NBK + 1) * 4);
    int* gbase   = (int*)alloc((size_t)NBLK * NBK * 4);
    int* ghist   = (int*)alloc((size_t)NBLK * NBK * 4);
    int* col     = (int*)alloc((size_t)NE * 4);
    unsigned short* XB  = (unsigned short*)alloc((size_t)MPAD * 128 * 2);   // 25.6MB
    unsigned short* BT0 = (unsigned short*)alloc(128 * 256 * 2);
    unsigned short* BT1 = (unsigned short*)alloc(128 * 256 * 2);
    unsigned short* BT2 = (unsigned short*)alloc(96 * 128 * 2);
    unsigned int* HNB   = (unsigned int*)alloc((size_t)MPAD * 128 * 2);     // 25.6MB (gather out)
    // S+TB region; eb (CSR build, 6.4MB) time-shares its head (dead before S/TB written)
    size_t sbytes  = (size_t)NN * 48 * 4;          // 19.2MB fp32 S
    size_t tbbytes = (size_t)MPAD * 64 * 2;        // 12.8MB bf16 TB (128B rows)
    char* stb = (char*)alloc(sbytes + tbbytes);
    unsigned int* eb   = (unsigned int*)stb;
    float* S           = (float*)stb;
    unsigned short* TB = (unsigned short*)(stb + sbytes);

    // --- CSR build + prep (hist launch also does cast + weight transposes) ---
    k_hist_prep<<<NBLK + PREPB, 256, 0, stream>>>(
        dst, ghist, (const float4*)x, (ushort4*)XB,
        Ws0, Wn0, BT0, Ws1, Wn1, BT1, Ws2, Wn2, BT2);
    k_basescan<<<1, 512, 0, stream>>>(ghist, boff, gbase);
    k_scatter<<<NBLK, 256, 0, stream>>>(src, dst, gbase, eb);
    k_csr<<<NBK, 256, 0, stream>>>(eb, boff, row_ptr, col);

    int mgrid = MPAD / 128;   // 782

    // --- layer 0 (bf16 in-place over XB) ---
    k_gather128<<<GBLK, 256, 0, stream>>>((const uint4*)XB, row_ptr, col, (uint4*)HNB);
    k_mgemm<<<mgrid, 256, 0, stream>>>(XB, (const unsigned short*)HNB, BT0, b0, XB);
    // --- layer 1 + layer-2 transform (fused; h2 in-place over XB, S/TB out) ---
    k_gather128<<<GBLK, 256, 0, stream>>>((const uint4*)XB, row_ptr, col, (uint4*)HNB);
    k_mgemm_l12<<<mgrid, 256, 0, stream>>>(XB, (const unsigned short*)HNB, BT1, b1, XB,
                                           BT2, b2, S, TB);
    // --- layer 2 aggregate ---
    k_gather47<<<GBLK, 256, 0, stream>>>((const uint2*)TB, (const float4*)S,
                                         row_ptr, col, out);
}